// Round 15
// baseline (137.657 us; speedup 1.0000x reference)
//
#include <hip/hip_runtime.h>
#include <math.h>

#define T_LEN 2097152
#define K 8
#define D 4
#define CHUNK 8
#define TPB 256
#define NBLK (T_LEN / (CHUNK * TPB))  // 1024 blocks
#define HSTRIDE 33                    // LDS slot stride in uints (32 half2 + 1 pad)

typedef float f2 __attribute__((ext_vector_type(2)));
typedef __fp16 h2 __attribute__((ext_vector_type(2)));

__device__ __forceinline__ f2 fma2(f2 a, f2 b, f2 c) { return __builtin_elementwise_fma(a, b, c); }
__device__ __forceinline__ f2 max2(f2 a, f2 b) { return __builtin_elementwise_max(a, b); }
__device__ __forceinline__ f2 splat(float s) { f2 r; r.x = s; r.y = s; return r; }
__device__ __forceinline__ unsigned pk(float a, float b) {
    h2 h = __builtin_amdgcn_cvt_pkrtz(a, b);
    return __builtin_bit_cast(unsigned, h);
}
__device__ __forceinline__ f2 upk(unsigned u) {
    h2 h = __builtin_bit_cast(h2, u);
    f2 r; r.x = (float)h.x; r.y = (float)h.y; return r;
}

// ws layout (floats): [0..63] Tr; [64..71] a; [72..103] b; [104..135] c; [136..143] alpha0
// [256..) bp (NBLK*64 floats), then bs (NBLK floats)

__device__ __forceinline__ void renorm_matf(float P[K][K], float& shift) {
    float mx = 0.f;
#pragma unroll
    for (int i = 0; i < K; ++i)
#pragma unroll
        for (int j = 0; j < K; ++j) mx = fmaxf(mx, P[i][j]);
    int ex = (__float_as_int(mx) >> 23) & 255;
    float scale = __int_as_float((254 - ex) << 23); // 2^(127-ex)
    shift += (float)(ex - 127);
#pragma unroll
    for (int i = 0; i < K; ++i)
#pragma unroll
        for (int j = 0; j < K; ++j) P[i][j] *= scale;
}

__device__ __forceinline__ void combine_stream(const float* __restrict__ Lp,
                                               const float* __restrict__ Rp,
                                               float C[K][K]) {
#pragma unroll
    for (int k = 0; k < K; ++k) {
        float Lc[K], Rr[K];
#pragma unroll
        for (int i = 0; i < K; ++i) Lc[i] = Lp[i * 8 + k];
#pragma unroll
        for (int j = 0; j < K; ++j) Rr[j] = Rp[k * 8 + j];
        if (k == 0) {
#pragma unroll
            for (int i = 0; i < K; ++i)
#pragma unroll
                for (int j = 0; j < K; ++j) C[i][j] = Lc[i] * Rr[j];
        } else {
#pragma unroll
            for (int i = 0; i < K; ++i)
#pragma unroll
                for (int j = 0; j < K; ++j) C[i][j] = fmaf(Lc[i], Rr[j], C[i][j]);
        }
    }
}

// Rows-parallel reduction of 128 time-ordered fp16 matrices in LDS -> slot 0.
// 8 lanes per combine (one output row each); R reads broadcast across the group.
__device__ __forceinline__ void tree_levels(unsigned* lmh, float* lsh) {
    const int g = threadIdx.x >> 3; // group 0..31
    const int i = threadIdx.x & 7;  // output row
#pragma unroll 1
    for (int lvl = 1; lvl <= 7; ++lvl) {
        const int c = 64 >> (lvl - 1);
        const int S = 1 << (lvl - 1);
#pragma unroll 1
        for (int m = g; m < c; m += 32) {
            const int li = 2 * m * S, ri = li + S;
            const unsigned* Lp = lmh + li * HSTRIDE;
            const unsigned* Rp = lmh + ri * HSTRIDE;
            f2 Lr2[4];
#pragma unroll
            for (int c4 = 0; c4 < 4; ++c4) Lr2[c4] = upk(Lp[i * 4 + c4]);
            float Lr[8] = {Lr2[0].x, Lr2[0].y, Lr2[1].x, Lr2[1].y,
                           Lr2[2].x, Lr2[2].y, Lr2[3].x, Lr2[3].y};
            f2 q2[4];
#pragma unroll
            for (int jj = 0; jj < 4; ++jj) q2[jj] = splat(Lr[0]) * upk(Rp[jj]);
#pragma unroll
            for (int k = 1; k < 8; ++k) {
                f2 rk = splat(Lr[k]);
#pragma unroll
                for (int jj = 0; jj < 4; ++jj) q2[jj] = fma2(rk, upk(Rp[k * 4 + jj]), q2[jj]);
            }
            f2 m2 = max2(max2(q2[0], q2[1]), max2(q2[2], q2[3]));
            float mx = fmaxf(m2.x, m2.y);
            mx = fmaxf(mx, __shfl_xor(mx, 1));
            mx = fmaxf(mx, __shfl_xor(mx, 2));
            mx = fmaxf(mx, __shfl_xor(mx, 4));
            int ex = (__float_as_int(mx) >> 23) & 255;
            float scale = __int_as_float((254 - ex) << 23);
            float ns = lsh[li] + lsh[ri] + (float)(ex - 127); // reads precede lane-0 write
            unsigned* Op = lmh + li * HSTRIDE + i * 4;
#pragma unroll
            for (int jj = 0; jj < 4; ++jj) Op[jj] = pk(q2[jj].x * scale, q2[jj].y * scale);
            if (i == 0) lsh[li] = ns;
        }
        __syncthreads();
    }
}

// Level 1 (256 reg-resident f2 mats -> 128 fp16 LDS slots, masked) + rows-parallel levels
__device__ __forceinline__ void hybrid_tree2(f2 P2[K][4], float& shift, unsigned* lmh, float* lsh) {
    const int t = threadIdx.x;
    if ((t & 1) == 0) {
        unsigned* sp = lmh + (t >> 1) * HSTRIDE;
#pragma unroll
        for (int i = 0; i < K; ++i)
#pragma unroll
            for (int jj = 0; jj < 4; ++jj) sp[i * 4 + jj] = pk(P2[i][jj].x, P2[i][jj].y);
        lsh[t >> 1] = shift;
    }
    __syncthreads();
    if (t & 1) {
        const unsigned* Lp = lmh + (t >> 1) * HSTRIDE;
        f2 C2[K][4];
#pragma unroll
        for (int i = 0; i < K; ++i) {
            f2 Lr2[4];
#pragma unroll
            for (int c4 = 0; c4 < 4; ++c4) Lr2[c4] = upk(Lp[i * 4 + c4]);
            float Lr[8] = {Lr2[0].x, Lr2[0].y, Lr2[1].x, Lr2[1].y,
                           Lr2[2].x, Lr2[2].y, Lr2[3].x, Lr2[3].y};
            f2 u[4];
#pragma unroll
            for (int jj = 0; jj < 4; ++jj) u[jj] = splat(Lr[0]) * P2[0][jj];
#pragma unroll
            for (int k = 1; k < 8; ++k) {
                f2 rk = splat(Lr[k]);
#pragma unroll
                for (int jj = 0; jj < 4; ++jj) u[jj] = fma2(rk, P2[k][jj], u[jj]);
            }
#pragma unroll
            for (int jj = 0; jj < 4; ++jj) C2[i][jj] = u[jj];
        }
        f2 mx2 = splat(0.f);
#pragma unroll
        for (int i = 0; i < K; ++i)
#pragma unroll
            for (int jj = 0; jj < 4; ++jj) mx2 = max2(mx2, C2[i][jj]);
        float mx = fmaxf(mx2.x, mx2.y);
        int ex = (__float_as_int(mx) >> 23) & 255;
        float scale = __int_as_float((254 - ex) << 23);
        float ns = shift + lsh[t >> 1] + (float)(ex - 127);
        unsigned* Op = lmh + (t >> 1) * HSTRIDE;
#pragma unroll
        for (int i = 0; i < K; ++i)
#pragma unroll
            for (int jj = 0; jj < 4; ++jj) Op[i * 4 + jj] = pk(C2[i][jj].x * scale, C2[i][jj].y * scale);
        lsh[t >> 1] = ns;
    }
    __syncthreads();
    tree_levels(lmh, lsh);
}

// packed emission: e2[4] = exp2(em - max), returns max (state pairs in f2)
__device__ __forceinline__ float emit_e2(const f2 ca2[4], const f2 cb2[4][4],
                                         const f2 cc2[4][4], float4 x, f2 e2[4]) {
    f2 x0 = splat(x.x), x1 = splat(x.y), x2 = splat(x.z), x3 = splat(x.w);
    f2 em2[4];
#pragma unroll
    for (int jj = 0; jj < 4; ++jj) {
        f2 t = ca2[jj];
        t = fma2(fma2(cc2[0][jj], x0, cb2[0][jj]), x0, t);
        t = fma2(fma2(cc2[1][jj], x1, cb2[1][jj]), x1, t);
        t = fma2(fma2(cc2[2][jj], x2, cb2[2][jj]), x2, t);
        t = fma2(fma2(cc2[3][jj], x3, cb2[3][jj]), x3, t);
        em2[jj] = t;
    }
    f2 m2 = max2(max2(em2[0], em2[1]), max2(em2[2], em2[3]));
    float me = fmaxf(m2.x, m2.y);
#pragma unroll
    for (int jj = 0; jj < 4; ++jj) {
        e2[jj].x = exp2f(em2[jj].x - me);
        e2[jj].y = exp2f(em2[jj].y - me);
    }
    return me;
}

// 64-thread parallel setup (keeps main's consts uniform -> SGPR)
__global__ void hmm_setup(const float* __restrict__ x,
                          const float* __restrict__ ut,
                          const float* __restrict__ up,
                          const float* __restrict__ mn,
                          const float* __restrict__ lsd,
                          float* __restrict__ ws) {
    const int lane = threadIdx.x;
    const float L2PI = 1.83787706640934548356f;
    const float LOG2E = 1.44269504088896340736f;

    float v = ut[lane];
    float m = v;
    m = fmaxf(m, __shfl_xor(m, 1));
    m = fmaxf(m, __shfl_xor(m, 2));
    m = fmaxf(m, __shfl_xor(m, 4));
    float e = expf(v - m);
    float s = e;
    s += __shfl_xor(s, 1); s += __shfl_xor(s, 2); s += __shfl_xor(s, 4);
    ws[lane] = e / s;

    float pv = up[lane & 7];
    float pm = pv;
    pm = fmaxf(pm, __shfl_xor(pm, 1));
    pm = fmaxf(pm, __shfl_xor(pm, 2));
    pm = fmaxf(pm, __shfl_xor(pm, 4));
    float pe = expf(pv - pm);
    float ps = pe;
    ps += __shfl_xor(ps, 1); ps += __shfl_xor(ps, 2); ps += __shfl_xor(ps, 4);
    float pival = pe / ps;

    int k = (lane & 31) >> 2, d = lane & 3;
    float lv = lsd[k * D + d];
    float mu = mn[k * D + d];
    float iv = expf(-2.f * lv);
    float bn = mu * iv;
    float cn = -0.5f * iv;
    float aterm = -0.5f * L2PI - lv - 0.5f * mu * mu * iv;
    float ak = aterm;
    ak += __shfl_xor(ak, 1); ak += __shfl_xor(ak, 2);
    if (lane < 32) {
        ws[72 + lane]  = bn * LOG2E;
        ws[104 + lane] = cn * LOG2E;
        if (d == 0) ws[64 + k] = ak * LOG2E;
    }

    float xd = x[d];
    float part = (cn * xd + bn) * xd + aterm;
    part += __shfl_xor(part, 1); part += __shfl_xor(part, 2);
    float pik = __shfl(pival, k);
    if (lane < 32 && d == 0) ws[136 + k] = pik * expf(part);
}

__global__ __launch_bounds__(TPB) void hmm_main(const float* __restrict__ x,
                                                const float* __restrict__ cst,
                                                float* __restrict__ bp,
                                                float* __restrict__ bs) {
    __shared__ unsigned lmh[128 * HSTRIDE]; // fp16 tree storage (16.9 KB)
    __shared__ float lsh[128];
    const int tid = blockIdx.x * TPB + threadIdx.x;

    float Tr[K][K]; // scalar view (uniform -> SGPR)
#pragma unroll
    for (int i = 0; i < K; ++i)
#pragma unroll
        for (int j = 0; j < K; ++j) Tr[i][j] = cst[i * K + j];
    f2 Tr2[K][4];   // packed column-pair view
#pragma unroll
    for (int i = 0; i < K; ++i)
#pragma unroll
        for (int jj = 0; jj < 4; ++jj) { Tr2[i][jj].x = Tr[i][2 * jj]; Tr2[i][jj].y = Tr[i][2 * jj + 1]; }

    f2 ca2[4], cb2[4][4], cc2[4][4]; // [d][state-pair]
#pragma unroll
    for (int jj = 0; jj < 4; ++jj) {
        ca2[jj].x = cst[64 + 2 * jj]; ca2[jj].y = cst[64 + 2 * jj + 1];
#pragma unroll
        for (int d = 0; d < 4; ++d) {
            cb2[d][jj].x = cst[72 + (2 * jj) * 4 + d];  cb2[d][jj].y = cst[72 + (2 * jj + 1) * 4 + d];
            cc2[d][jj].x = cst[104 + (2 * jj) * 4 + d]; cc2[d][jj].y = cst[104 + (2 * jj + 1) * 4 + d];
        }
    }

    // full-chunk register prefetch: one latency exposure per chunk
    const float4* xv = reinterpret_cast<const float4*>(x) + (size_t)tid * CHUNK;
    float4 xr[CHUNK];
#pragma unroll
    for (int t = 0; t < CHUNK; ++t) xr[t] = xv[t];

    // Chunk transfer = Tr*S0*S1*S2*S3, S=(D_a·Tr·D_b); T packed as f2[8][4]
    f2 T2[K][4];
    float shift;
    {
        f2 eB[4];
        float meB = emit_e2(ca2, cb2, cc2, xr[1], eB);
        if (tid == 0) {
#pragma unroll
            for (int i = 0; i < K; ++i) {
                f2 a0 = splat(cst[136 + i]);
#pragma unroll
                for (int jj = 0; jj < 4; ++jj) T2[i][jj] = a0 * Tr2[i][jj] * eB[jj];
            }
            shift = meB;
        } else {
            f2 eA[4];
            float meA = emit_e2(ca2, cb2, cc2, xr[0], eA);
#pragma unroll
            for (int i = 0; i < K; ++i) {
                f2 ei = splat((i & 1) ? eA[i >> 1].y : eA[i >> 1].x);
#pragma unroll
                for (int jj = 0; jj < 4; ++jj) T2[i][jj] = ei * Tr2[i][jj] * eB[jj];
            }
            shift = meA + meB;
        }
    }

#pragma unroll
    for (int p = 1; p < 4; ++p) {
        f2 eA[4], eB[4];
        float meA = emit_e2(ca2, cb2, cc2, xr[2 * p], eA);
        float meB = emit_e2(ca2, cb2, cc2, xr[2 * p + 1], eB);
        shift += meA + meB;
        // T <- ((T .col eA) * Tr) .col eB, row-wise in place
#pragma unroll
        for (int i = 0; i < K; ++i) {
            f2 r2[4];
#pragma unroll
            for (int kk = 0; kk < 4; ++kk) r2[kk] = T2[i][kk] * eA[kk];
            f2 u[4];
#pragma unroll
            for (int jj = 0; jj < 4; ++jj) u[jj] = splat(r2[0].x) * Tr2[0][jj];
#pragma unroll
            for (int k = 1; k < 8; ++k) {
                f2 rk = splat((k & 1) ? r2[k >> 1].y : r2[k >> 1].x);
#pragma unroll
                for (int jj = 0; jj < 4; ++jj) u[jj] = fma2(rk, Tr2[k][jj], u[jj]);
            }
#pragma unroll
            for (int jj = 0; jj < 4; ++jj) T2[i][jj] = u[jj] * eB[jj];
        }
    }

    if (tid != 0) {
        // T <- Tr * T, column-pair in place
#pragma unroll
        for (int jj = 0; jj < 4; ++jj) {
            f2 c[K];
#pragma unroll
            for (int k = 0; k < K; ++k) c[k] = T2[k][jj];
#pragma unroll
            for (int i = 0; i < K; ++i) {
                f2 a = splat(Tr[i][0]) * c[0];
#pragma unroll
                for (int k = 1; k < K; ++k) a = fma2(splat(Tr[i][k]), c[k], a);
                T2[i][jj] = a;
            }
        }
    }

    float (*T)[K] = reinterpret_cast<float(*)[K]>(T2); // layout-compatible
    renorm_matf(T, shift);

    hybrid_tree2(T2, shift, lmh, lsh);

    if (threadIdx.x == 0) {
        float* o = bp + (size_t)blockIdx.x * 64;
#pragma unroll
        for (int i = 0; i < K; ++i)
#pragma unroll
            for (int jj = 0; jj < 4; ++jj) {
                f2 v = upk(lmh[i * 4 + jj]);
                o[i * 8 + 2 * jj] = v.x;
                o[i * 8 + 2 * jj + 1] = v.y;
            }
        bs[blockIdx.x] = lsh[0];
    }
}

// 256-thread final: 4 serial fp32 combines per thread, then the fp16 hybrid tree
__global__ void hmm_final(const float* __restrict__ bp,
                          const float* __restrict__ bs,
                          float* __restrict__ out) {
    __shared__ unsigned lmh[128 * HSTRIDE];
    __shared__ float lsh[128];
    const int t = threadIdx.x;
    const int base = t * 4;

    float P[K][K];
    {
        const float4* p4 = reinterpret_cast<const float4*>(bp + (size_t)base * 64);
        float4* dst = reinterpret_cast<float4*>(&P[0][0]);
#pragma unroll
        for (int q = 0; q < 16; ++q) dst[q] = p4[q];
    }
    float shift = bs[base];
#pragma unroll 1
    for (int r = 1; r < 4; ++r) {
        const float* Rp = bp + (size_t)(base + r) * 64;
        float C[K][K];
        combine_stream(&P[0][0], Rp, C);
        shift += bs[base + r];
        renorm_matf(C, shift);
#pragma unroll
        for (int i = 0; i < K; ++i)
#pragma unroll
            for (int j = 0; j < K; ++j) P[i][j] = C[i][j];
    }

    f2 (*P2)[4] = reinterpret_cast<f2(*)[4]>(P);
    hybrid_tree2(P2, shift, lmh, lsh);

    if (t == 0) {
        double s = 0.0;
#pragma unroll
        for (int i = 0; i < K; ++i)
#pragma unroll
            for (int jj = 0; jj < 4; ++jj) {
                f2 v = upk(lmh[i * 4 + jj]);
                s += (double)v.x + (double)v.y;
            }
        out[0] = (float)(log(s) + (double)lsh[0] * 0.69314718055994530942);
    }
}

extern "C" void kernel_launch(void* const* d_in, const int* in_sizes, int n_in,
                              void* d_out, int out_size, void* d_ws, size_t ws_size,
                              hipStream_t stream) {
    (void)in_sizes; (void)n_in; (void)out_size; (void)ws_size;
    const float* x  = (const float*)d_in[0];
    const float* ut = (const float*)d_in[1];
    const float* up = (const float*)d_in[2];
    const float* mn = (const float*)d_in[3];
    const float* ls = (const float*)d_in[4];
    float* ws  = (float*)d_ws;
    float* out = (float*)d_out;
    float* bp  = ws + 256;
    float* bs  = ws + 256 + (size_t)NBLK * 64;

    hmm_setup<<<1, 64, 0, stream>>>(x, ut, up, mn, ls, ws);
    hmm_main<<<NBLK, TPB, 0, stream>>>(x, ws, bp, bs);
    hmm_final<<<1, TPB, 0, stream>>>(bp, bs, out);
}